// Round 3
// baseline (1574.946 us; speedup 1.0000x reference)
//
#include <hip/hip_runtime.h>

#define TT 128
#define NB 64
#define NSZ 32
#define MSZ 8
#define PSZ 16
#define LD 36
#define LDC 20

__device__ __forceinline__ void fma4(float4& a, float s, const float4 v){
  a.x = fmaf(s, v.x, a.x);
  a.y = fmaf(s, v.y, a.y);
  a.z = fmaf(s, v.z, a.z);
  a.w = fmaf(s, v.w, a.w);
}
__device__ __forceinline__ float frcp(float x){ return __builtin_amdgcn_rcpf(x); }

// ============ Forward Kalman filter: 1 WAVE per batch, no barriers ============
__global__ __launch_bounds__(64) void kf_forward(
    const float* __restrict__ Yg, const float* __restrict__ Ug,
    const float* __restrict__ Ag, const float* __restrict__ Bg,
    const float* __restrict__ Cg, const float* __restrict__ mu0g,
    const float* __restrict__ Sig0g,
    float* __restrict__ outg, float* __restrict__ wsSig, float* __restrict__ wsMu)
{
  const int l = threadIdx.x;
  const int b = blockIdx.x;
  const int rt = l >> 3, ct = l & 7;
  const int r0 = rt << 2, c0 = ct << 2;     // 4x4 tile for 32x32 outputs
  const int rt2 = l >> 3;                   // rows 2*rt2,2*rt2+1 for 16-row outputs
  const int rp = l >> 3, cp = l & 7;        // 2x2 tile for 16x16 S
  const int row = l & 15, g = l >> 4;       // GJ mapping

  __shared__ float SigL [NSZ][LD];
  __shared__ float ATs  [NSZ][LD];
  __shared__ float T1T  [NSZ][LD];   // also reused as transpose scratch in sym
  __shared__ float SigpL[NSZ][LD];
  __shared__ float CT   [NSZ][LDC];
  __shared__ float CST  [NSZ][LDC];
  __shared__ float CSL  [PSZ][LD];
  __shared__ float KtL  [PSZ][LD];
  __shared__ float SL   [PSZ][LDC];
  __shared__ float BsL  [NSZ][12];
  __shared__ float muv[NSZ], mupv[NSZ], rv[PSZ], yv[PSZ], uvv[MSZ];

  const size_t bt0 = (size_t)b * TT;
  const int rA = l >> 1, cA = (l & 1) << 4;   // A/Sig load: half-row per lane
  const int rC = l >> 2, cC = (l & 3) << 3;   // C load: quarter-row per lane
  const int rB = l >> 1, cB = (l & 1) << 2;   // B load

  // ---- init: Sigma0, mu0, t=0 inputs ----
  #pragma unroll
  for (int q = 0; q < 4; ++q)
    *(float4*)&SigL[rA][cA + 4*q] = *(const float4*)(Sig0g + rA*32 + cA + 4*q);
  if (l < 32) muv[l] = mu0g[l];
  #pragma unroll
  for (int q = 0; q < 4; ++q){
    float4 v = *(const float4*)(Ag + bt0*1024 + rA*32 + cA + 4*q);
    ATs[cA+4*q+0][rA]=v.x; ATs[cA+4*q+1][rA]=v.y; ATs[cA+4*q+2][rA]=v.z; ATs[cA+4*q+3][rA]=v.w;
  }
  #pragma unroll
  for (int q = 0; q < 2; ++q){
    float4 v = *(const float4*)(Cg + bt0*512 + rC*32 + cC + 4*q);
    CT[cC+4*q+0][rC]=v.x; CT[cC+4*q+1][rC]=v.y; CT[cC+4*q+2][rC]=v.z; CT[cC+4*q+3][rC]=v.w;
  }
  *(float4*)&BsL[rB][cB] = *(const float4*)(Bg + bt0*256 + rB*8 + cB);
  if (l < 16) yv[l] = Yg[bt0*16 + l];
  if (l < 8)  uvv[l] = Ug[bt0*8 + l];

  for (int t = 0; t < TT; ++t) {
    const size_t bt = bt0 + t;
    // ---- prefetch next-step inputs into registers ----
    float4 pa[4], pc[2], pb; float py = 0.f, pu = 0.f;
    if (t + 1 < TT) {
      #pragma unroll
      for (int q=0;q<4;++q) pa[q] = *(const float4*)(Ag + (bt+1)*1024 + rA*32 + cA + 4*q);
      #pragma unroll
      for (int q=0;q<2;++q) pc[q] = *(const float4*)(Cg + (bt+1)*512 + rC*32 + cC + 4*q);
      pb = *(const float4*)(Bg + (bt+1)*256 + rB*8 + cB);
      if (l < 16) py = Yg[(bt+1)*16 + l];
      if (l < 8)  pu = Ug[(bt+1)*8 + l];
    } else {
      pa[0]=pa[1]=pa[2]=pa[3]=make_float4(0.f,0.f,0.f,0.f);
      pc[0]=pc[1]=make_float4(0.f,0.f,0.f,0.f);
      pb=make_float4(0.f,0.f,0.f,0.f);
    }

    // ---- Phase 1: T1 = A*Sig (store transposed) ; mu_p = A*mu + B*u ----
    float4 t0=make_float4(0.f,0.f,0.f,0.f), t1=t0, t2=t0, t3=t0;
    #pragma unroll
    for (int k=0;k<32;++k){
      float4 a = *(const float4*)&ATs[k][r0];      // A[r0+i][k]
      float4 s = *(const float4*)&SigL[k][c0];     // Sig[k][c0+j]
      fma4(t0,a.x,s); fma4(t1,a.y,s); fma4(t2,a.z,s); fma4(t3,a.w,s);
    }
    T1T[c0+0][r0+0]=t0.x; T1T[c0+1][r0+0]=t0.y; T1T[c0+2][r0+0]=t0.z; T1T[c0+3][r0+0]=t0.w;
    T1T[c0+0][r0+1]=t1.x; T1T[c0+1][r0+1]=t1.y; T1T[c0+2][r0+1]=t1.z; T1T[c0+3][r0+1]=t1.w;
    T1T[c0+0][r0+2]=t2.x; T1T[c0+1][r0+2]=t2.y; T1T[c0+2][r0+2]=t2.z; T1T[c0+3][r0+2]=t2.w;
    T1T[c0+0][r0+3]=t3.x; T1T[c0+1][r0+3]=t3.y; T1T[c0+2][r0+3]=t3.z; T1T[c0+3][r0+3]=t3.w;
    if (l < 32){
      float m = 0.f;
      #pragma unroll
      for (int k=0;k<32;++k) m = fmaf(ATs[k][l], muv[k], m);
      #pragma unroll
      for (int k=0;k<8;++k)  m = fmaf(BsL[l][k], uvv[k], m);
      mupv[l] = m;
    }

    // ---- Phase 2: Sig_p = T1*A^T + Q ; store to LDS + workspace ----
    float4 sp0=make_float4(0.f,0.f,0.f,0.f), sp1=sp0, sp2=sp0, sp3=sp0;
    #pragma unroll
    for (int k=0;k<32;++k){
      float4 tv = *(const float4*)&T1T[k][r0];     // T1[r0+i][k]
      float4 av = *(const float4*)&ATs[k][c0];     // A[c0+j][k]
      fma4(sp0,tv.x,av); fma4(sp1,tv.y,av); fma4(sp2,tv.z,av); fma4(sp3,tv.w,av);
    }
    if (rt == ct){ sp0.x += 0.01f; sp1.y += 0.01f; sp2.z += 0.01f; sp3.w += 0.01f; }
    *(float4*)&SigpL[r0+0][c0]=sp0; *(float4*)&SigpL[r0+1][c0]=sp1;
    *(float4*)&SigpL[r0+2][c0]=sp2; *(float4*)&SigpL[r0+3][c0]=sp3;
    {
      float* wp = wsSig + (bt*32 + r0)*32 + c0;
      *(float4*)(wp)      = sp0; *(float4*)(wp+32) = sp1;
      *(float4*)(wp+64)   = sp2; *(float4*)(wp+96) = sp3;
      if (l < 32) wsMu[bt*32 + l] = mupv[l];
    }

    // ---- Phase 3: CS = C*Sig_p ; r = y - C*mu_p ----
    float4 cs0=make_float4(0.f,0.f,0.f,0.f), cs1=cs0;
    #pragma unroll
    for (int k=0;k<32;++k){
      float2 cc = *(const float2*)&CT[k][2*rt2];   // C[2rt2+i][k]
      float4 s  = *(const float4*)&SigpL[k][c0];
      fma4(cs0,cc.x,s); fma4(cs1,cc.y,s);
    }
    *(float4*)&CSL[2*rt2+0][c0] = cs0;
    *(float4*)&CSL[2*rt2+1][c0] = cs1;
    *(float2*)&CST[c0+0][2*rt2] = make_float2(cs0.x, cs1.x);
    *(float2*)&CST[c0+1][2*rt2] = make_float2(cs0.y, cs1.y);
    *(float2*)&CST[c0+2][2*rt2] = make_float2(cs0.z, cs1.z);
    *(float2*)&CST[c0+3][2*rt2] = make_float2(cs0.w, cs1.w);
    if (l < 16){
      float r = yv[l];
      #pragma unroll
      for (int k=0;k<32;++k) r = fmaf(-CT[k][l], mupv[k], r);
      rv[l] = r;
    }

    // ---- Phase 4: S = CS*C^T + R (16x16, 2x2 tiles) ----
    {
      float sa=0.f, sb=0.f, sc=0.f, sd=0.f;
      #pragma unroll
      for (int k=0;k<32;++k){
        float2 a = *(const float2*)&CST[k][2*rp];  // CS[2rp+i][k]
        float2 c = *(const float2*)&CT [k][2*cp];  // C[2cp+j][k]
        sa=fmaf(a.x,c.x,sa); sb=fmaf(a.x,c.y,sb);
        sc=fmaf(a.y,c.x,sc); sd=fmaf(a.y,c.y,sd);
      }
      if (rp == cp){ sa += 0.01f; sd += 0.01f; }
      SL[2*rp+0][2*cp+0]=sa; SL[2*rp+0][2*cp+1]=sb;
      SL[2*rp+1][2*cp+0]=sc; SL[2*rp+1][2*cp+1]=sd;
    }

    // ---- Phase 5: register Gauss-Jordan on [sym(S) | CS] (16x48), shuffles only ----
    {
      float aug[16];
      if (g == 0){
        float tmp[16];
        #pragma unroll
        for (int q=0;q<4;++q){
          float4 v = *(const float4*)&SL[row][4*q];
          tmp[4*q]=v.x; tmp[4*q+1]=v.y; tmp[4*q+2]=v.z; tmp[4*q+3]=v.w;
        }
        #pragma unroll
        for (int c2=0;c2<16;++c2) aug[c2] = 0.5f*(tmp[c2] + SL[c2][row]);
      } else if (g <= 2){
        #pragma unroll
        for (int q=0;q<4;++q){
          float4 v = *(const float4*)&CSL[row][(g-1)*16 + 4*q];
          aug[4*q]=v.x; aug[4*q+1]=v.y; aug[4*q+2]=v.z; aug[4*q+3]=v.w;
        }
      } else {
        #pragma unroll
        for (int c2=0;c2<16;++c2) aug[c2] = 0.f;
      }
      const int psrc = g << 4;
      #pragma unroll
      for (int k=0;k<16;++k){
        float f   = __shfl(aug[k], row);        // Aug[row][k] (col k lives in g=0)
        float piv = __shfl(aug[k], k);          // Aug[k][k]
        float prc = frcp(piv);
        float pr[16];
        #pragma unroll
        for (int c2=0;c2<16;++c2) pr[c2] = __shfl(aug[c2], k + psrc); // pivot row, my cols
        float fn = f * prc;
        #pragma unroll
        for (int c2=0;c2<16;++c2){
          float upd = fmaf(-fn, pr[c2], aug[c2]);
          aug[c2] = (row == k) ? aug[c2]*prc : upd;
        }
      }
      if (g == 1){
        #pragma unroll
        for (int q=0;q<4;++q)
          *(float4*)&KtL[row][4*q] = make_float4(aug[4*q],aug[4*q+1],aug[4*q+2],aug[4*q+3]);
      } else if (g == 2){
        #pragma unroll
        for (int q=0;q<4;++q)
          *(float4*)&KtL[row][16+4*q] = make_float4(aug[4*q],aug[4*q+1],aug[4*q+2],aug[4*q+3]);
      }
    }

    // ---- Phase 6: Sig_f = sym(Sig_p - K*CS) ; mu_f ; outputs ----
    {
      float4 f0=sp0, f1=sp1, f2=sp2, f3=sp3;
      #pragma unroll
      for (int p=0;p<16;++p){
        float4 kt = *(const float4*)&KtL[p][r0];  // K[r0+i][p]
        float4 cs = *(const float4*)&CSL[p][c0];  // CS[p][c0+j]
        fma4(f0,-kt.x,cs); fma4(f1,-kt.y,cs); fma4(f2,-kt.z,cs); fma4(f3,-kt.w,cs);
      }
      *(float4*)&T1T[r0+0][c0]=f0; *(float4*)&T1T[r0+1][c0]=f1;
      *(float4*)&T1T[r0+2][c0]=f2; *(float4*)&T1T[r0+3][c0]=f3;
      float4 w0,w1,w2,w3;
      w0.x=0.5f*(f0.x+T1T[c0+0][r0+0]); w0.y=0.5f*(f0.y+T1T[c0+1][r0+0]);
      w0.z=0.5f*(f0.z+T1T[c0+2][r0+0]); w0.w=0.5f*(f0.w+T1T[c0+3][r0+0]);
      w1.x=0.5f*(f1.x+T1T[c0+0][r0+1]); w1.y=0.5f*(f1.y+T1T[c0+1][r0+1]);
      w1.z=0.5f*(f1.z+T1T[c0+2][r0+1]); w1.w=0.5f*(f1.w+T1T[c0+3][r0+1]);
      w2.x=0.5f*(f2.x+T1T[c0+0][r0+2]); w2.y=0.5f*(f2.y+T1T[c0+1][r0+2]);
      w2.z=0.5f*(f2.z+T1T[c0+2][r0+2]); w2.w=0.5f*(f2.w+T1T[c0+3][r0+2]);
      w3.x=0.5f*(f3.x+T1T[c0+0][r0+3]); w3.y=0.5f*(f3.y+T1T[c0+1][r0+3]);
      w3.z=0.5f*(f3.z+T1T[c0+2][r0+3]); w3.w=0.5f*(f3.w+T1T[c0+3][r0+3]);
      *(float4*)&SigL[r0+0][c0]=w0; *(float4*)&SigL[r0+1][c0]=w1;
      *(float4*)&SigL[r0+2][c0]=w2; *(float4*)&SigL[r0+3][c0]=w3;
      float* op = outg + (bt*32 + r0)*33 + 1 + c0;
      op[0]=w0.x; op[1]=w0.y; op[2]=w0.z; op[3]=w0.w; op+=33;
      op[0]=w1.x; op[1]=w1.y; op[2]=w1.z; op[3]=w1.w; op+=33;
      op[0]=w2.x; op[1]=w2.y; op[2]=w2.z; op[3]=w2.w; op+=33;
      op[0]=w3.x; op[1]=w3.y; op[2]=w3.z; op[3]=w3.w;
      if (l < 32){
        float m = mupv[l];
        #pragma unroll
        for (int p=0;p<16;++p) m = fmaf(KtL[p][l], rv[p], m);
        muv[l] = m;
        outg[(bt*32 + l)*33] = m;
      }
    }

    // ---- Phase 7: stage next-step inputs into LDS ----
    if (t + 1 < TT){
      #pragma unroll
      for (int q=0;q<4;++q){
        float4 v = pa[q];
        ATs[cA+4*q+0][rA]=v.x; ATs[cA+4*q+1][rA]=v.y; ATs[cA+4*q+2][rA]=v.z; ATs[cA+4*q+3][rA]=v.w;
      }
      #pragma unroll
      for (int q=0;q<2;++q){
        float4 v = pc[q];
        CT[cC+4*q+0][rC]=v.x; CT[cC+4*q+1][rC]=v.y; CT[cC+4*q+2][rC]=v.z; CT[cC+4*q+3][rC]=v.w;
      }
      *(float4*)&BsL[rB][cB] = pb;
      if (l < 16) yv[l] = py;
      if (l < 8)  uvv[l] = pu;
    }
  }
}

// ------- Parallel smoother precompute: J_t, E_t, e_t for t=0..T-2 (unchanged) -------
__global__ __launch_bounds__(256) void kf_precomp(
    const float* __restrict__ Ag, float* __restrict__ outg,
    float* __restrict__ wsSig, float* __restrict__ wsMu)
{
  const int t = blockIdx.x;
  const int b = blockIdx.y;
  const int tid = threadIdx.x;
  const int i32 = tid >> 3;
  const int j4 = (tid & 7) << 2;
  __shared__ __align__(16) float Sf[NSZ][LD];
  __shared__ __align__(16) float AT2[NSZ][LD];
  __shared__ __align__(16) float Mm[NSZ][LD];
  __shared__ __align__(16) float Pm[NSZ][LD];
  __shared__ __align__(16) float V[NSZ][LD];
  __shared__ __align__(16) float Jl[NSZ][LD];
  __shared__ __align__(16) float JTs[NSZ][LD];
  __shared__ __align__(16) float prow[NSZ];
  __shared__ __align__(16) float vrow[NSZ];
  __shared__ float mfv[NSZ], mp1[NSZ];
  const size_t bt = (size_t)b*TT + t;
  {
    const float* os = outg + bt*NSZ*(NSZ+1);
    #pragma unroll
    for (int r = 0; r < 4; ++r) {
      int e = tid + 256*r; int i = e >> 5, j = e & 31;
      Sf[i][j] = os[i*(NSZ+1) + 1 + j];
    }
    if (tid < NSZ) mfv[tid] = os[tid*(NSZ+1)];
    float4 a4 = *(const float4*)(Ag + bt*(NSZ*NSZ) + tid*4);
    AT2[j4+0][i32]=a4.x; AT2[j4+1][i32]=a4.y; AT2[j4+2][i32]=a4.z; AT2[j4+3][i32]=a4.w;
    *(float4*)&Pm[i32][j4] = *(const float4*)(wsSig + ((bt+1)*NSZ + i32)*NSZ + j4);
    if (tid < NSZ) mp1[tid] = wsMu[(bt+1)*NSZ + tid];
    float4 vi;
    vi.x = (i32 == j4+0) ? 1.f : 0.f;
    vi.y = (i32 == j4+1) ? 1.f : 0.f;
    vi.z = (i32 == j4+2) ? 1.f : 0.f;
    vi.w = (i32 == j4+3) ? 1.f : 0.f;
    *(float4*)&V[i32][j4] = vi;
  }
  __syncthreads();
  {
    float4 acc = make_float4(0.f,0.f,0.f,0.f);
    #pragma unroll
    for (int k0 = 0; k0 < NSZ; k0 += 4) {
      float4 s = *(const float4*)&Sf[i32][k0];
      fma4(acc, s.x, *(const float4*)&AT2[k0+0][j4]);
      fma4(acc, s.y, *(const float4*)&AT2[k0+1][j4]);
      fma4(acc, s.z, *(const float4*)&AT2[k0+2][j4]);
      fma4(acc, s.w, *(const float4*)&AT2[k0+3][j4]);
    }
    *(float4*)&Mm[i32][j4] = acc;
  }
  __syncthreads();
  for (int k = 0; k < NSZ; ++k) {
    float f = Pm[i32][k];
    if (tid < 8) {
      float rd = frcp(Pm[k][k]);
      #pragma unroll
      for (int m = 0; m < 4; ++m) prow[tid*4+m] = Pm[k][tid*4+m] * rd;
    } else if (tid < 16) {
      float rd = frcp(Pm[k][k]);
      const int c0 = (tid-8)*4;
      #pragma unroll
      for (int m = 0; m < 4; ++m) vrow[c0+m] = V[k][c0+m] * rd;
    }
    __syncthreads();
    if (i32 == k) {
      *(float4*)&Pm[k][j4] = *(const float4*)&prow[j4];
      *(float4*)&V[k][j4] = *(const float4*)&vrow[j4];
    } else {
      float4 p = *(const float4*)&Pm[i32][j4];
      float4 v = *(const float4*)&V[i32][j4];
      fma4(p, -f, *(const float4*)&prow[j4]);
      fma4(v, -f, *(const float4*)&vrow[j4]);
      *(float4*)&Pm[i32][j4] = p;
      *(float4*)&V[i32][j4] = v;
    }
    __syncthreads();
  }
  {
    float4 acc = make_float4(0.f,0.f,0.f,0.f);
    #pragma unroll
    for (int k0 = 0; k0 < NSZ; k0 += 4) {
      float4 m4 = *(const float4*)&Mm[i32][k0];
      fma4(acc, m4.x, *(const float4*)&V[k0+0][j4]);
      fma4(acc, m4.y, *(const float4*)&V[k0+1][j4]);
      fma4(acc, m4.z, *(const float4*)&V[k0+2][j4]);
      fma4(acc, m4.w, *(const float4*)&V[k0+3][j4]);
    }
    *(float4*)&Jl[i32][j4] = acc;
    JTs[j4+0][i32]=acc.x; JTs[j4+1][i32]=acc.y; JTs[j4+2][i32]=acc.z; JTs[j4+3][i32]=acc.w;
    *(float4*)(wsSig + ((bt+1)*NSZ + i32)*NSZ + j4) = acc;
  }
  __syncthreads();
  {
    float4 acc = make_float4(0.f,0.f,0.f,0.f);
    #pragma unroll
    for (int k0 = 0; k0 < NSZ; k0 += 4) {
      float4 m4 = *(const float4*)&Mm[i32][k0];
      fma4(acc, m4.x, *(const float4*)&JTs[k0+0][j4]);
      fma4(acc, m4.y, *(const float4*)&JTs[k0+1][j4]);
      fma4(acc, m4.z, *(const float4*)&JTs[k0+2][j4]);
      fma4(acc, m4.w, *(const float4*)&JTs[k0+3][j4]);
    }
    float* os = outg + bt*NSZ*(NSZ+1);
    os[i32*(NSZ+1)+1+j4+0] = Sf[i32][j4+0] - acc.x;
    os[i32*(NSZ+1)+1+j4+1] = Sf[i32][j4+1] - acc.y;
    os[i32*(NSZ+1)+1+j4+2] = Sf[i32][j4+2] - acc.z;
    os[i32*(NSZ+1)+1+j4+3] = Sf[i32][j4+3] - acc.w;
    if (tid < NSZ) {
      float e2 = mfv[tid];
      #pragma unroll
      for (int k = 0; k < NSZ; ++k) e2 = fmaf(-Jl[tid][k], mp1[k], e2);
      os[tid*(NSZ+1)] = e2;
    }
  }
}

// ============ Backward smoother: 1 WAVE per batch, no barriers ============
__global__ __launch_bounds__(64) void kf_backward(
    float* __restrict__ outg, const float* __restrict__ wsSig)
{
  const int l = threadIdx.x;
  const int b = blockIdx.x;
  const int rt = l >> 3, ct = l & 7;
  const int r0 = rt << 2, c0 = ct << 2;
  const int rA = l >> 1, cA = (l & 1) << 4;
  __shared__ float SigsL[NSZ][LD];
  __shared__ float JT [NSZ][LD];
  __shared__ float WT [NSZ][LD];
  __shared__ float Tt [NSZ][LD];
  __shared__ float muv[NSZ], evv[NSZ];
  const size_t base = (size_t)b * TT;

  // init: Sigs = Sig_f[T-1], mus = mu_f[T-1]; J slot T-1; E/e of t=T-2
  {
    const float* os = outg + (base + TT - 1)*32*33;
    #pragma unroll
    for (int c = 0; c < 16; ++c) SigsL[rA][cA + c] = os[rA*33 + 1 + cA + c];
    if (l < 32) muv[l] = os[l*33];
    #pragma unroll
    for (int q = 0; q < 4; ++q){
      float4 v = *(const float4*)(wsSig + ((base + TT - 1)*32 + rA)*32 + cA + 4*q);
      JT[cA+4*q+0][rA]=v.x; JT[cA+4*q+1][rA]=v.y; JT[cA+4*q+2][rA]=v.z; JT[cA+4*q+3][rA]=v.w;
    }
  }
  float er[4][4];
  {
    const float* oe = outg + (base + TT - 2)*32*33;
    #pragma unroll
    for (int i=0;i<4;++i)
      #pragma unroll
      for (int j=0;j<4;++j) er[i][j] = oe[(r0+i)*33 + 1 + c0 + j];
    if (l < 32) evv[l] = oe[l*33];
  }

  for (int t = TT - 2; t >= 0; --t) {
    // prefetch next iteration's J (slot base+t => J_{t-1}) and E/e of t-1
    float4 pj[4]; float ne[4][4]; float nev = 0.f;
    if (t > 0) {
      #pragma unroll
      for (int q=0;q<4;++q)
        pj[q] = *(const float4*)(wsSig + ((base + t)*32 + rA)*32 + cA + 4*q);
      const float* oe = outg + (base + t - 1)*32*33;
      #pragma unroll
      for (int i=0;i<4;++i)
        #pragma unroll
        for (int j=0;j<4;++j) ne[i][j] = oe[(r0+i)*33 + 1 + c0 + j];
      if (l < 32) nev = oe[l*33];
    } else {
      pj[0]=pj[1]=pj[2]=pj[3]=make_float4(0.f,0.f,0.f,0.f);
      #pragma unroll
      for (int i=0;i<4;++i){ ne[i][0]=0.f; ne[i][1]=0.f; ne[i][2]=0.f; ne[i][3]=0.f; }
    }

    // W = J * Sigs  (store transposed)
    float4 w0=make_float4(0.f,0.f,0.f,0.f), w1=w0, w2=w0, w3=w0;
    #pragma unroll
    for (int k=0;k<32;++k){
      float4 jv = *(const float4*)&JT[k][r0];      // J[r0+i][k]
      float4 sv = *(const float4*)&SigsL[k][c0];
      fma4(w0,jv.x,sv); fma4(w1,jv.y,sv); fma4(w2,jv.z,sv); fma4(w3,jv.w,sv);
    }
    WT[c0+0][r0+0]=w0.x; WT[c0+1][r0+0]=w0.y; WT[c0+2][r0+0]=w0.z; WT[c0+3][r0+0]=w0.w;
    WT[c0+0][r0+1]=w1.x; WT[c0+1][r0+1]=w1.y; WT[c0+2][r0+1]=w1.z; WT[c0+3][r0+1]=w1.w;
    WT[c0+0][r0+2]=w2.x; WT[c0+1][r0+2]=w2.y; WT[c0+2][r0+2]=w2.z; WT[c0+3][r0+2]=w2.w;
    WT[c0+0][r0+3]=w3.x; WT[c0+1][r0+3]=w3.y; WT[c0+2][r0+3]=w3.z; WT[c0+3][r0+3]=w3.w;

    // G = E + W * J^T ; sym ; mu update
    float4 g0=make_float4(0.f,0.f,0.f,0.f), g1=g0, g2=g0, g3=g0;
    #pragma unroll
    for (int k=0;k<32;++k){
      float4 wv = *(const float4*)&WT[k][r0];      // W[r0+i][k]
      float4 ju = *(const float4*)&JT[k][c0];      // J[c0+j][k]
      fma4(g0,wv.x,ju); fma4(g1,wv.y,ju); fma4(g2,wv.z,ju); fma4(g3,wv.w,ju);
    }
    g0.x+=er[0][0]; g0.y+=er[0][1]; g0.z+=er[0][2]; g0.w+=er[0][3];
    g1.x+=er[1][0]; g1.y+=er[1][1]; g1.z+=er[1][2]; g1.w+=er[1][3];
    g2.x+=er[2][0]; g2.y+=er[2][1]; g2.z+=er[2][2]; g2.w+=er[2][3];
    g3.x+=er[3][0]; g3.y+=er[3][1]; g3.z+=er[3][2]; g3.w+=er[3][3];
    *(float4*)&Tt[r0+0][c0]=g0; *(float4*)&Tt[r0+1][c0]=g1;
    *(float4*)&Tt[r0+2][c0]=g2; *(float4*)&Tt[r0+3][c0]=g3;

    float mn = 0.f;
    if (l < 32){
      mn = evv[l];
      #pragma unroll
      for (int k=0;k<32;++k) mn = fmaf(JT[k][l], muv[k], mn);
    }

    float4 o0,o1,o2,o3;
    o0.x=0.5f*(g0.x+Tt[c0+0][r0+0]); o0.y=0.5f*(g0.y+Tt[c0+1][r0+0]);
    o0.z=0.5f*(g0.z+Tt[c0+2][r0+0]); o0.w=0.5f*(g0.w+Tt[c0+3][r0+0]);
    o1.x=0.5f*(g1.x+Tt[c0+0][r0+1]); o1.y=0.5f*(g1.y+Tt[c0+1][r0+1]);
    o1.z=0.5f*(g1.z+Tt[c0+2][r0+1]); o1.w=0.5f*(g1.w+Tt[c0+3][r0+1]);
    o2.x=0.5f*(g2.x+Tt[c0+0][r0+2]); o2.y=0.5f*(g2.y+Tt[c0+1][r0+2]);
    o2.z=0.5f*(g2.z+Tt[c0+2][r0+2]); o2.w=0.5f*(g2.w+Tt[c0+3][r0+2]);
    o3.x=0.5f*(g3.x+Tt[c0+0][r0+3]); o3.y=0.5f*(g3.y+Tt[c0+1][r0+3]);
    o3.z=0.5f*(g3.z+Tt[c0+2][r0+3]); o3.w=0.5f*(g3.w+Tt[c0+3][r0+3]);
    *(float4*)&SigsL[r0+0][c0]=o0; *(float4*)&SigsL[r0+1][c0]=o1;
    *(float4*)&SigsL[r0+2][c0]=o2; *(float4*)&SigsL[r0+3][c0]=o3;
    {
      float* op = outg + ((base + t)*32 + r0)*33 + 1 + c0;
      op[0]=o0.x; op[1]=o0.y; op[2]=o0.z; op[3]=o0.w; op+=33;
      op[0]=o1.x; op[1]=o1.y; op[2]=o1.z; op[3]=o1.w; op+=33;
      op[0]=o2.x; op[1]=o2.y; op[2]=o2.z; op[3]=o2.w; op+=33;
      op[0]=o3.x; op[1]=o3.y; op[2]=o3.z; op[3]=o3.w;
    }
    if (l < 32){
      muv[l] = mn;
      outg[((base + t)*32 + l)*33] = mn;
    }

    // stage next J / E / e
    if (t > 0){
      #pragma unroll
      for (int q=0;q<4;++q){
        float4 v = pj[q];
        JT[cA+4*q+0][rA]=v.x; JT[cA+4*q+1][rA]=v.y; JT[cA+4*q+2][rA]=v.z; JT[cA+4*q+3][rA]=v.w;
      }
      #pragma unroll
      for (int i=0;i<4;++i)
        #pragma unroll
        for (int j=0;j<4;++j) er[i][j] = ne[i][j];
      if (l < 32) evv[l] = nev;
    }
  }
}

extern "C" void kernel_launch(void* const* d_in, const int* in_sizes, int n_in,
                              void* d_out, int out_size, void* d_ws, size_t ws_size,
                              hipStream_t stream) {
  (void)in_sizes; (void)n_in; (void)out_size; (void)ws_size;
  const float* Yg   = (const float*)d_in[0];
  const float* Ug   = (const float*)d_in[1];
  const float* Ag   = (const float*)d_in[2];
  const float* Bg   = (const float*)d_in[3];
  const float* Cg   = (const float*)d_in[4];
  const float* mu0g = (const float*)d_in[5];
  const float* S0g  = (const float*)d_in[6];
  float* outg = (float*)d_out;
  float* wsSig = (float*)d_ws;                              // B*T*N*N floats
  float* wsMu  = wsSig + (size_t)NB*TT*NSZ*NSZ;             // B*T*N floats

  hipLaunchKernelGGL(kf_forward, dim3(NB), dim3(64), 0, stream,
                     Yg, Ug, Ag, Bg, Cg, mu0g, S0g, outg, wsSig, wsMu);
  hipLaunchKernelGGL(kf_precomp, dim3(TT-1, NB), dim3(256), 0, stream,
                     Ag, outg, wsSig, wsMu);
  hipLaunchKernelGGL(kf_backward, dim3(NB), dim3(64), 0, stream,
                     outg, wsSig);
}